// Round 2
// baseline (188.323 us; speedup 1.0000x reference)
//
#include <hip/hip_runtime.h>
#include <math.h>

#define EPS 1e-6f
#define TAU 1.0f

// Full per-box loss. Same math as the verified v1/v2 kernels
// (passed absmax 3.9e-3 with __sincosf/__logf/__frcp_rn).
__device__ __forceinline__ float box_loss(float px, float py, float pw, float ph, float pr,
                                          float tx, float ty, float tw, float th, float tr) {
    pw = fminf(fmaxf(pw, 1e-7f), 1e7f);
    ph = fminf(fmaxf(ph, 1e-7f), 1e7f);
    tw = fminf(fmaxf(tw, 1e-7f), 1e7f);
    th = fminf(fmaxf(th, 1e-7f), 1e7f);

    float pa = 0.25f * pw * pw, pb = 0.25f * ph * ph;
    float ta = 0.25f * tw * tw, tb = 0.25f * th * th;

    float ps, pc, ts, tc;
    __sincosf(pr, &ps, &pc);
    __sincosf(tr, &ts, &tc);

    float p11 = pa * pc * pc + pb * ps * ps;
    float p12 = (pa - pb) * ps * pc;
    float p22 = pa * ps * ps + pb * pc * pc;
    float t11 = ta * tc * tc + tb * ts * ts;
    float t12 = (ta - tb) * ts * tc;
    float t22 = ta * ts * ts + tb * tc * tc;

    float det_p = p11 * p22 - p12 * p12;
    float det_t = t11 * t22 - t12 * t12;

    float dx = px - tx;
    float dy = py - ty;

    float inv_det_t = __frcp_rn(det_t);
    float term1 = (t22 * dx * dx - 2.0f * t12 * dx * dy + t11 * dy * dy) * inv_det_t;
    float trace_term = (t22 * p11 - 2.0f * t12 * p12 + t11 * p22) * inv_det_t;
    float term2 = trace_term + __logf(det_t) - __logf(det_p);

    float dis = term1 + term2 - 2.0f;
    float kl = fmaxf(dis, EPS);
    return 1.0f - __frcp_rn(TAU + sqrtf(kl));
}

// 8 boxes per thread: 8 boxes x 5 floats = 10 aligned float4 loads per array.
// ALL 20 loads are issued before any compute (sched_barrier pins the order),
// so the wave has ~20 KB in flight; first waitcnt is a counted vmcnt and
// later boxes' loads stay outstanding under the early boxes' math.
__global__ void __launch_bounds__(256) gd_loss_kernel8(
        const float4* __restrict__ pred4,
        const float4* __restrict__ tgt4,
        float4* __restrict__ out4, int n8) {
    int i = blockIdx.x * blockDim.x + threadIdx.x;
    if (i >= n8) return;

    const float4* p = pred4 + (size_t)i * 10;   // 160 B per thread, 16 B aligned
    const float4* t = tgt4  + (size_t)i * 10;

    float4 a0 = p[0], a1 = p[1], a2 = p[2], a3 = p[3], a4 = p[4];
    float4 a5 = p[5], a6 = p[6], a7 = p[7], a8 = p[8], a9 = p[9];
    float4 b0 = t[0], b1 = t[1], b2 = t[2], b3 = t[3], b4 = t[4];
    float4 b5 = t[5], b6 = t[6], b7 = t[7], b8 = t[8], b9 = t[9];

    // No instruction may cross this point: all 20 global loads issue first.
    __builtin_amdgcn_sched_barrier(0);

    float4 r0, r1;
    r0.x = box_loss(a0.x, a0.y, a0.z, a0.w, a1.x,
                    b0.x, b0.y, b0.z, b0.w, b1.x);
    r0.y = box_loss(a1.y, a1.z, a1.w, a2.x, a2.y,
                    b1.y, b1.z, b1.w, b2.x, b2.y);
    r0.z = box_loss(a2.z, a2.w, a3.x, a3.y, a3.z,
                    b2.z, b2.w, b3.x, b3.y, b3.z);
    r0.w = box_loss(a3.w, a4.x, a4.y, a4.z, a4.w,
                    b3.w, b4.x, b4.y, b4.z, b4.w);
    r1.x = box_loss(a5.x, a5.y, a5.z, a5.w, a6.x,
                    b5.x, b5.y, b5.z, b5.w, b6.x);
    r1.y = box_loss(a6.y, a6.z, a6.w, a7.x, a7.y,
                    b6.y, b6.z, b6.w, b7.x, b7.y);
    r1.z = box_loss(a7.z, a7.w, a8.x, a8.y, a8.z,
                    b7.z, b7.w, b8.x, b8.y, b8.z);
    r1.w = box_loss(a8.w, a9.x, a9.y, a9.z, a9.w,
                    b8.w, b9.x, b9.y, b9.z, b9.w);

    out4[(size_t)i * 2]     = r0;
    out4[(size_t)i * 2 + 1] = r1;
}

// Scalar tail for n % 8 boxes (not hit at N = 4,000,000; defensive).
__global__ void __launch_bounds__(64) gd_loss_tail(
        const float* __restrict__ pred,
        const float* __restrict__ tgt,
        float* __restrict__ out, int start, int n) {
    int i = start + blockIdx.x * blockDim.x + threadIdx.x;
    if (i >= n) return;
    const float* p = pred + (size_t)i * 5;
    const float* t = tgt  + (size_t)i * 5;
    out[i] = box_loss(p[0], p[1], p[2], p[3], p[4],
                      t[0], t[1], t[2], t[3], t[4]);
}

extern "C" void kernel_launch(void* const* d_in, const int* in_sizes, int n_in,
                              void* d_out, int out_size, void* d_ws, size_t ws_size,
                              hipStream_t stream) {
    const float* pred = (const float*)d_in[0];
    const float* tgt  = (const float*)d_in[1];
    float* out = (float*)d_out;
    int n = out_size;  // N boxes, one loss per box

    int n8 = n >> 3;
    int rem = n & 7;

    if (n8 > 0) {
        int block = 256;
        int grid = (n8 + block - 1) / block;
        gd_loss_kernel8<<<grid, block, 0, stream>>>(
            (const float4*)pred, (const float4*)tgt, (float4*)out, n8);
    }
    if (rem > 0) {
        gd_loss_tail<<<1, 64, 0, stream>>>(pred, tgt, out, n8 << 3, n);
    }
}

// Round 3
// 185.404 us; speedup vs baseline: 1.0157x; 1.0157x over previous
//
#include <hip/hip_runtime.h>
#include <math.h>

#define EPS 1e-6f
#define TAU 1.0f

// Full per-box loss. Same math as the verified v1-v3 kernels
// (passed absmax 3.9e-3 with __sincosf/__logf/__frcp_rn).
__device__ __forceinline__ float box_loss(float px, float py, float pw, float ph, float pr,
                                          float tx, float ty, float tw, float th, float tr) {
    pw = fminf(fmaxf(pw, 1e-7f), 1e7f);
    ph = fminf(fmaxf(ph, 1e-7f), 1e7f);
    tw = fminf(fmaxf(tw, 1e-7f), 1e7f);
    th = fminf(fmaxf(th, 1e-7f), 1e7f);

    float pa = 0.25f * pw * pw, pb = 0.25f * ph * ph;
    float ta = 0.25f * tw * tw, tb = 0.25f * th * th;

    float ps, pc, ts, tc;
    __sincosf(pr, &ps, &pc);
    __sincosf(tr, &ts, &tc);

    float p11 = pa * pc * pc + pb * ps * ps;
    float p12 = (pa - pb) * ps * pc;
    float p22 = pa * ps * ps + pb * pc * pc;
    float t11 = ta * tc * tc + tb * ts * ts;
    float t12 = (ta - tb) * ts * tc;
    float t22 = ta * ts * ts + tb * tc * tc;

    float det_p = p11 * p22 - p12 * p12;
    float det_t = t11 * t22 - t12 * t12;

    float dx = px - tx;
    float dy = py - ty;

    float inv_det_t = __frcp_rn(det_t);
    float term1 = (t22 * dx * dx - 2.0f * t12 * dx * dy + t11 * dy * dy) * inv_det_t;
    float trace_term = (t22 * p11 - 2.0f * t12 * p12 + t11 * p22) * inv_det_t;
    float term2 = trace_term + __logf(det_t) - __logf(det_p);

    float dis = term1 + term2 - 2.0f;
    float kl = fmaxf(dis, EPS);
    return 1.0f - __frcp_rn(TAU + sqrtf(kl));
}

// AoS -> LDS -> SoA: each 256-thread block stages its 256 boxes (2 x 5120 B)
// with DENSE float4 loads (lane i <-> base + 16 B * i, the exact 6.3 TB/s copy
// pattern), then each thread reads its 10 floats from LDS.
// LDS stride-5 float reads: bank = (5t + j) mod 32, gcd(5,32)=1 -> exactly
// 2 lanes/bank per wave64 access = conflict-free (m136).
__global__ void __launch_bounds__(256) gd_loss_lds(
        const float* __restrict__ pred,
        const float* __restrict__ tgt,
        float* __restrict__ out, int n) {
    __shared__ float sp[1280];   // 256 boxes * 5 floats
    __shared__ float st[1280];

    const int b = blockIdx.x;
    const int t = threadIdx.x;
    const size_t fbase = (size_t)b * 1280;     // first float of this block
    const size_t nf = (size_t)n * 5;           // total floats per array

    // 320 float4s per array per block; threads 0..255 take k, threads 0..63 take 256+k.
    #pragma unroll
    for (int k = t; k < 320; k += 256) {
        size_t f = fbase + (size_t)k * 4;
        if (f + 3 < nf) {
            float4 vp = *reinterpret_cast<const float4*>(pred + f);
            float4 vt = *reinterpret_cast<const float4*>(tgt + f);
            *reinterpret_cast<float4*>(sp + k * 4) = vp;
            *reinterpret_cast<float4*>(st + k * 4) = vt;
        } else {                                // ragged tail (not hit at N=4M)
            for (int j = 0; j < 4; ++j) {
                size_t f2 = f + j;
                if (f2 < nf) {
                    sp[k * 4 + j] = pred[f2];
                    st[k * 4 + j] = tgt[f2];
                }
            }
        }
    }
    __syncthreads();

    int i = b * 256 + t;
    if (i >= n) return;

    const float* p = sp + t * 5;
    const float* q = st + t * 5;
    out[i] = box_loss(p[0], p[1], p[2], p[3], p[4],
                      q[0], q[1], q[2], q[3], q[4]);
}

extern "C" void kernel_launch(void* const* d_in, const int* in_sizes, int n_in,
                              void* d_out, int out_size, void* d_ws, size_t ws_size,
                              hipStream_t stream) {
    const float* pred = (const float*)d_in[0];
    const float* tgt  = (const float*)d_in[1];
    float* out = (float*)d_out;
    int n = out_size;  // N boxes, one loss per box

    int block = 256;
    int grid = (n + block - 1) / block;
    gd_loss_lds<<<grid, block, 0, stream>>>(pred, tgt, out, n);
}